// Round 1
// baseline (294.706 us; speedup 1.0000x reference)
//
#include <hip/hip_runtime.h>

// Problem constants: B=64, S=512, D=256
#define NEG_INF (-4294967295.0f)   // matches ref: -(2**32)+1 rounded to f32

typedef _Float16 f16;
typedef _Float16 f16x8 __attribute__((ext_vector_type(8)));
typedef _Float16 f16x4v __attribute__((ext_vector_type(4)));
typedef float f32x4 __attribute__((ext_vector_type(4)));

#define MFMA16(a, b, c) __builtin_amdgcn_mfma_f32_16x16x32_f16((a), (b), (c), 0, 0, 0)

// --- LDS index helpers (f16 element units), XOR-swizzled for bank spread ---
// [rows][256] tiles (A, W^T, K): swizzle chunk-of-8 by row&7  (G4 fix for 512B row stride)
__device__ __forceinline__ int aswz(int row, int d) { return (row << 8) + (d ^ ((row & 7) << 3)); }
// V^T tile [256 d][32 k]: swizzle k chunk by (d>>2)&3 (write lanes vary d by 4)
__device__ __forceinline__ int vti(int d, int k) { return (d << 5) + (k ^ (((d >> 2) & 3) << 3)); }
// P tile [16 q][32 k]
__device__ __forceinline__ int pidx(int q, int c) { return (q << 5) + (c ^ ((q & 3) << 3)); }

// ---------------------------------------------------------------------------
// Kernel 0: sinusoidal positional encoding table, f32 [512][256]
// ---------------------------------------------------------------------------
__global__ __launch_bounds__(256) void pe_kernel(float* __restrict__ pe) {
    int idx = blockIdx.x * 256 + threadIdx.x;
    if (idx >= 512 * 256) return;
    int s = idx >> 8, d = idx & 255;
    float rate = powf(10000.f, -(float)(2 * (d >> 1)) / 256.f);
    float ang = (float)s * rate;
    pe[idx] = (d & 1) ? cosf(ang) : sinf(ang);
}

// ---------------------------------------------------------------------------
// Kernel 1: projection  out[r, e] = relu( sum_d (src[r,d]+pe[r%512,d]) * W[d,e] )
// rows 0..32767 from q, 32768..65535 from k. Output f16.
// grid (1024 row-tiles of 64, 4 col-tiles of 64), 256 threads (4 waves).
// ---------------------------------------------------------------------------
__global__ __launch_bounds__(256) void proj_kernel(const float* __restrict__ q,
                                                   const float* __restrict__ k,
                                                   const float* __restrict__ W,
                                                   const float* __restrict__ pe,
                                                   f16* __restrict__ out) {
    __shared__ __align__(16) f16 As[64 * 256];   // A tile, swizzled
    __shared__ __align__(16) f16 Ws[64 * 256];   // W^T tile: Ws[e][d], swizzled
    int tid = threadIdx.x;
    int l = tid & 63, w = tid >> 6;
    int lr = l & 15, lg = l >> 4;
    int gr0 = blockIdx.x * 64;
    int n0 = blockIdx.y * 64;
    const float* src = (gr0 < 32768) ? q : k;
    int r0 = gr0 & 32767;

    // stage A = src + PE, f32 -> f16 (coalesced 1KB/row per wave)
    #pragma unroll
    for (int it = 0; it < 16; ++it) {
        int r = it * 4 + w;
        int d = (tid & 63) * 4;
        int s = (r0 + r) & 511;
        float4 av = *(const float4*)(src + (size_t)(r0 + r) * 256 + d);
        float4 pv = *(const float4*)(pe + s * 256 + d);
        f16x4v hv;
        hv[0] = (f16)(av.x + pv.x); hv[1] = (f16)(av.y + pv.y);
        hv[2] = (f16)(av.z + pv.z); hv[3] = (f16)(av.w + pv.w);
        *(f16x4v*)&As[aswz(r, d)] = hv;
    }
    // stage W^T: Ws[e][d] = W[d][n0+e]  (coalesced reads, scattered f16 writes)
    for (int it = 0; it < 64; ++it) {
        int d = it * 4 + w;
        Ws[aswz(l, d)] = (f16)W[d * 256 + n0 + l];
    }
    __syncthreads();

    f32x4 acc[4] = {};
    #pragma unroll
    for (int kk = 0; kk < 8; ++kk) {
        int dk = kk * 32 + lg * 8;
        f16x8 a = *(const f16x8*)&As[aswz(w * 16 + lr, dk)];
        #pragma unroll
        for (int nt = 0; nt < 4; ++nt) {
            f16x8 b = *(const f16x8*)&Ws[aswz(nt * 16 + lr, dk)];
            acc[nt] = MFMA16(a, b, acc[nt]);
        }
    }
    // epilogue: relu -> f16 store. D layout: row=(lg*4+reg), col=lr (m89-verified)
    int gr_base = gr0 + w * 16 + lg * 4;
    #pragma unroll
    for (int nt = 0; nt < 4; ++nt) {
        #pragma unroll
        for (int rg = 0; rg < 4; ++rg) {
            float v = acc[nt][rg];
            v = v > 0.f ? v : 0.f;
            out[(size_t)(gr_base + rg) * 256 + n0 + nt * 16 + lr] = (f16)v;
        }
    }
}

// ---------------------------------------------------------------------------
// Kernel 2: flash attention + mean over q.
// grid (8 q-tiles, 64 batches), 256 threads = 4 waves, each wave owns 16 q-rows.
// K/V staged per 32-kpos tile in LDS; online softmax in registers.
// out[b,d] += sum_q O[q,d]/l[q] / 512  via atomics (out pre-zeroed).
// ---------------------------------------------------------------------------
__global__ __launch_bounds__(256) void attn_kernel(const f16* __restrict__ QP,
                                                   const f16* __restrict__ KP,
                                                   const float* __restrict__ V,
                                                   const int* __restrict__ mask,
                                                   float* __restrict__ out) {
    __shared__ __align__(16) f16 Ks[32 * 256];   // K tile  [kpos][d], swizzled
    __shared__ __align__(16) f16 Vt[256 * 32];   // V^T tile [d][kpos], swizzled
    __shared__ __align__(16) f16 Pw[4][16 * 32]; // per-wave P tile [q][kpos]

    int tid = threadIdx.x;
    int l = tid & 63, wv = tid >> 6;
    int lr = l & 15, lg = l >> 4;
    int bb = blockIdx.y;
    int q0 = blockIdx.x * 64 + wv * 16;

    // Q fragments: lane lr holds row q0+lr, 8 d-chunks of 8
    f16x8 qf[8];
    const f16* qrow = QP + ((size_t)(bb * 512 + q0 + lr)) * 256;
    #pragma unroll
    for (int kk = 0; kk < 8; ++kk) qf[kk] = *(const f16x8*)(qrow + kk * 32 + lg * 8);

    f32x4 O[16] = {};          // 16 d-tiles x 4 rows
    float m[4], ls[4];
    #pragma unroll
    for (int r = 0; r < 4; ++r) { m[r] = -INFINITY; ls[r] = 0.f; }

    for (int kt = 0; kt < 16; ++kt) {
        __syncthreads();   // previous tile's LDS reads complete
        // stage K tile (f16 source, coalesced 512B/row)
        #pragma unroll
        for (int it = 0; it < 4; ++it) {
            int r = it * 8 + (tid >> 5);
            int d = (tid & 31) * 8;
            f16x8 kv = *(const f16x8*)(KP + ((size_t)(bb * 512 + kt * 32 + r)) * 256 + d);
            *(f16x8*)&Ks[aswz(r, d)] = kv;
        }
        // stage V^T tile (f32 source, coalesced reads, transposed f16 writes)
        #pragma unroll
        for (int it = 0; it < 8; ++it) {
            int r = it * 4 + (tid >> 6);
            int d = (tid & 63) * 4;
            float4 vv = *(const float4*)(V + ((size_t)(bb * 512 + kt * 32 + r)) * 256 + d);
            Vt[vti(d + 0, r)] = (f16)vv.x;
            Vt[vti(d + 1, r)] = (f16)vv.y;
            Vt[vti(d + 2, r)] = (f16)vv.z;
            Vt[vti(d + 3, r)] = (f16)vv.w;
        }
        __syncthreads();

        // S = Q K^T for 32 kpos (two 16-wide n-tiles), f32 accum
        f32x4 s0 = {}, s1 = {};
        #pragma unroll
        for (int kk = 0; kk < 8; ++kk) {
            int dk = kk * 32 + lg * 8;
            f16x8 b0 = *(const f16x8*)&Ks[aswz(lr, dk)];
            f16x8 b1 = *(const f16x8*)&Ks[aswz(16 + lr, dk)];
            s0 = MFMA16(qf[kk], b0, s0);
            s1 = MFMA16(qf[kk], b1, s1);
        }
        int mbase = bb * 512 + kt * 32;
        int mk0 = mask[mbase + lr];
        int mk1 = mask[mbase + 16 + lr];

        // online softmax per q-row; lane l owns rows lg*4+rg, col lr (+16)
        float fsc[4];
        #pragma unroll
        for (int rg = 0; rg < 4; ++rg) {
            float v0 = mk0 ? s0[rg] * 0.0625f : NEG_INF;   // /sqrt(256)
            float v1 = mk1 ? s1[rg] * 0.0625f : NEG_INF;
            float t = fmaxf(v0, v1);
            t = fmaxf(t, __shfl_xor(t, 1));
            t = fmaxf(t, __shfl_xor(t, 2));
            t = fmaxf(t, __shfl_xor(t, 4));
            t = fmaxf(t, __shfl_xor(t, 8));
            float mn = fmaxf(m[rg], t);
            float f = __expf(m[rg] - mn);     // m=-inf first iter -> 0; all-masked: exp(0)=1
            float p0 = __expf(v0 - mn);
            float p1 = __expf(v1 - mn);
            float rs = p0 + p1;
            rs += __shfl_xor(rs, 1);
            rs += __shfl_xor(rs, 2);
            rs += __shfl_xor(rs, 4);
            rs += __shfl_xor(rs, 8);
            ls[rg] = ls[rg] * f + rs;
            m[rg] = mn;
            fsc[rg] = f;
            int qq = lg * 4 + rg;
            Pw[wv][pidx(qq, lr)] = (f16)p0;
            Pw[wv][pidx(qq, 16 + lr)] = (f16)p1;
        }
        // rescale O
        #pragma unroll
        for (int nt = 0; nt < 16; ++nt) {
            #pragma unroll
            for (int rg = 0; rg < 4; ++rg) O[nt][rg] *= fsc[rg];
        }
        // PV: O[q, d] += P[q, kpos] * V[kpos, d]   (same-wave LDS RAW: DS in-order)
        f16x8 pa = *(const f16x8*)&Pw[wv][pidx(lr, lg * 8)];
        #pragma unroll
        for (int nt = 0; nt < 16; ++nt) {
            f16x8 vb = *(const f16x8*)&Vt[vti(nt * 16 + lr, lg * 8)];
            O[nt] = MFMA16(pa, vb, O[nt]);
        }
    }

    // epilogue: normalize, sum over this wave's 16 q-rows, atomic accumulate mean
    float rls[4];
    #pragma unroll
    for (int rg = 0; rg < 4; ++rg) rls[rg] = 1.0f / ls[rg];
    #pragma unroll
    for (int nt = 0; nt < 16; ++nt) {
        float v = 0.f;
        #pragma unroll
        for (int rg = 0; rg < 4; ++rg) v += O[nt][rg] * rls[rg];
        v += __shfl_xor(v, 16);
        v += __shfl_xor(v, 32);
        if (l < 16) atomicAdd(&out[bb * 256 + nt * 16 + l], v * (1.f / 512.f));
    }
}

// ---------------------------------------------------------------------------
extern "C" void kernel_launch(void* const* d_in, const int* in_sizes, int n_in,
                              void* d_out, int out_size, void* d_ws, size_t ws_size,
                              hipStream_t stream) {
    const float* q   = (const float*)d_in[0];
    const float* k   = (const float*)d_in[1];
    const float* v   = (const float*)d_in[2];
    const float* W   = (const float*)d_in[3];
    const int* mask  = (const int*)d_in[4];
    float* out = (float*)d_out;

    // workspace layout: QP f16 [32768,256] | KP f16 [32768,256] | PE f32 [512,256]
    f16* proj = (f16*)d_ws;
    float* pe = (float*)((char*)d_ws + (size_t)2 * 32768 * 256 * sizeof(f16));

    pe_kernel<<<512, 256, 0, stream>>>(pe);
    proj_kernel<<<dim3(1024, 4), 256, 0, stream>>>(q, k, W, pe, proj);
    hipMemsetAsync(d_out, 0, 64 * 256 * sizeof(float), stream);
    attn_kernel<<<dim3(8, 64), 256, 0, stream>>>(proj, proj + (size_t)32768 * 256, v, mask, out);
}

// Round 2
// 201.736 us; speedup vs baseline: 1.4609x; 1.4609x over previous
//
#include <hip/hip_runtime.h>

// B=64, S=512, D=256
#define NEG_INF (-4294967295.0f)

typedef _Float16 f16;
typedef _Float16 f16x8 __attribute__((ext_vector_type(8)));
typedef _Float16 f16x4v __attribute__((ext_vector_type(4)));
typedef float f32x4 __attribute__((ext_vector_type(4)));

#define MFMA16(a,b,c) __builtin_amdgcn_mfma_f32_16x16x32_f16((a),(b),(c),0,0,0)

#if defined(__has_builtin)
#if __has_builtin(__builtin_amdgcn_global_load_lds)
#define HAS_GLD 1
#endif
#endif

// async 16B global->LDS; dest = lds_base + lane*16 (wave-uniform base)
__device__ __forceinline__ void stage16(const void* g, void* lds_base, int lane) {
#ifdef HAS_GLD
    __builtin_amdgcn_global_load_lds(
        (const __attribute__((address_space(1))) unsigned int*)g,
        (__attribute__((address_space(3))) unsigned int*)lds_base, 16, 0, 0);
#else
    ((f16x8*)lds_base)[lane] = *(const f16x8*)g;
#endif
}

// ---------------------------------------------------------------------------
// PE table f32 [512][256]
// ---------------------------------------------------------------------------
__global__ __launch_bounds__(256) void pe_kernel(float* __restrict__ pe) {
    int idx = blockIdx.x * 256 + threadIdx.x;
    int s = idx >> 8, d = idx & 255;
    float x = (float)(d & ~1) * (1.f / 256.f);
    float rate = exp2f(x * -13.287712379549449f);   // 10000^-x
    float ang = (float)s * rate;
    pe[idx] = (d & 1) ? cosf(ang) : sinf(ang);
}

// W^T f16 [e][d] = W[d][e]
__global__ __launch_bounds__(256) void wt_kernel(const float* __restrict__ W,
                                                 f16* __restrict__ WT) {
    int e = blockIdx.x, d = threadIdx.x;
    WT[(e << 8) + d] = (f16)W[(d << 8) + e];
}

// V^T f16 [b][d=256][k=512] via LDS transpose (stride 269 breaks bank conflicts)
__global__ __launch_bounds__(256) void vt_kernel(const float* __restrict__ V,
                                                 f16* __restrict__ VT) {
    __shared__ float T[64 * 269];
    const int t = threadIdx.x;
    const int k0 = blockIdx.x * 64, bb = blockIdx.y;
    #pragma unroll
    for (int it = 0; it < 16; ++it) {
        int r = it * 4 + (t >> 6), d = (t & 63) * 4;
        float4 v = *(const float4*)(V + (((size_t)(bb * 512 + k0 + r)) << 8) + d);
        T[r * 269 + d + 0] = v.x; T[r * 269 + d + 1] = v.y;
        T[r * 269 + d + 2] = v.z; T[r * 269 + d + 3] = v.w;
    }
    __syncthreads();
    #pragma unroll
    for (int dr = 0; dr < 8; ++dr) {
        int d = dr * 32 + (t >> 3), c = t & 7;
        f16x8 o;
        #pragma unroll
        for (int j = 0; j < 8; ++j) o[j] = (f16)T[(c * 8 + j) * 269 + d];
        *(f16x8*)(VT + (((size_t)(bb * 256 + d)) << 9) + k0 + c * 8) = o;
    }
}

// ---------------------------------------------------------------------------
// Projection: rows 0..32767=q, 32768..65535=k. out = relu((x+pe)@W)*0.25, f16.
// Block = 64 rows x 256 cols, 4 waves (16 rows each), K double-buffered by 64.
// ---------------------------------------------------------------------------
__global__ __launch_bounds__(256) void proj_kernel(const float* __restrict__ q,
                                                   const float* __restrict__ k,
                                                   const f16* __restrict__ WT,
                                                   const float* __restrict__ pe,
                                                   f16* __restrict__ outp) {
    __shared__ __align__(16) f16 As[2][64 * 64];
    __shared__ __align__(16) f16 WTs[2][256 * 64];
    const int t = threadIdx.x, l = t & 63, wv = t >> 6, lr = l & 15, lg = l >> 4;
    const int r0 = blockIdx.x * 64;
    const float* src = (r0 < 32768) ? q : k;
    const int rb = r0 & 32767;

    float4 av[4], pv[4];
    auto loadA = [&](int kc) {
        #pragma unroll
        for (int it = 0; it < 4; ++it) {
            int r = it * 16 + (t >> 4), d = (t & 15) * 4;
            av[it] = *(const float4*)(src + (size_t)(rb + r) * 256 + kc * 64 + d);
            pv[it] = *(const float4*)(pe + ((rb + r) & 511) * 256 + kc * 64 + d);
        }
    };
    auto writeA = [&](int dst) {
        #pragma unroll
        for (int it = 0; it < 4; ++it) {
            int r = it * 16 + (t >> 4), d = (t & 15) * 4;
            f16x4v h;
            h[0] = (f16)(av[it].x + pv[it].x); h[1] = (f16)(av[it].y + pv[it].y);
            h[2] = (f16)(av[it].z + pv[it].z); h[3] = (f16)(av[it].w + pv[it].w);
            *(f16x4v*)&As[dst][(r << 6) + (d ^ ((r & 7) << 3))] = h;
        }
    };
    auto stageW = [&](int dst, int kc) {   // swizzle via per-lane source chunk
        #pragma unroll
        for (int it = 0; it < 8; ++it) {
            int eb = wv * 64 + it * 8;
            int e = eb + (l >> 3), c = l & 7;
            const f16* s = WT + (e << 8) + kc * 64 + ((c ^ (e & 7)) << 3);
            stage16(s, &WTs[dst][eb << 6], l);
        }
    };

    f32x4 acc[16] = {};
    loadA(0); stageW(0, 0); writeA(0);
    __syncthreads();

    for (int kc = 0; kc < 4; ++kc) {
        int cur = kc & 1;
        if (kc < 3) { loadA(kc + 1); stageW(cur ^ 1, kc + 1); }
        #pragma unroll
        for (int kk = 0; kk < 2; ++kk) {
            int dk = kk * 32 + lg * 8;
            f16x8 a = *(const f16x8*)&As[cur][((wv * 16 + lr) << 6) + (dk ^ ((lr & 7) << 3))];
            #pragma unroll
            for (int nt = 0; nt < 16; ++nt) {
                int e = nt * 16 + lr;
                f16x8 b = *(const f16x8*)&WTs[cur][(e << 6) + (dk ^ ((lr & 7) << 3))];
                acc[nt] = MFMA16(a, b, acc[nt]);
            }
        }
        if (kc < 3) { writeA(cur ^ 1); __syncthreads(); }
    }

    // epilogue: relu * 0.25 (folded 1/sqrt(D)), LDS bounce -> coalesced 16B stores.
    // WTs[0] quarter per wave is free: buf0 last read ended at the kc==2 barrier.
    f16* Rb = &WTs[0][0] + wv * 4096;
    #pragma unroll
    for (int nt = 0; nt < 16; ++nt) {
        #pragma unroll
        for (int rg = 0; rg < 4; ++rg) {
            int rr = lg * 4 + rg, col = nt * 16 + lr;
            float v = acc[nt][rg];
            v = v > 0.f ? v * 0.25f : 0.f;
            Rb[rr * 256 + ((((col >> 3) ^ (rr & 7)) << 3) | (col & 7))] = (f16)v;
        }
    }
    #pragma unroll
    for (int it = 0; it < 8; ++it) {
        int row = it * 2 + (l >> 5), c = l & 31;
        f16x8 v8 = *(const f16x8*)&Rb[row * 256 + ((c ^ (row & 7)) << 3)];
        *(f16x8*)(outp + (((size_t)(r0 + wv * 16 + row)) << 8) + c * 8) = v8;
    }
}

// ---------------------------------------------------------------------------
// Flash attention + mean over q. Flat grid 512: bb = n&63 (same-batch blocks
// share an XCD L2), qt = n>>6. 4 waves x 16 q-rows. 2-phase pipelined staging.
// ---------------------------------------------------------------------------
__global__ __launch_bounds__(256) void attn_kernel(const f16* __restrict__ QP,
                                                   const f16* __restrict__ KP,
                                                   const f16* __restrict__ VT,
                                                   const int* __restrict__ mask,
                                                   float* __restrict__ out) {
    __shared__ __align__(16) f16 Ks[2][32 * 256];
    __shared__ __align__(16) f16 Vs[2][256 * 32];
    __shared__ __align__(16) f16 Pw[4][16 * 32];
    const int t = threadIdx.x, l = t & 63, wv = t >> 6, lr = l & 15, lg = l >> 4;
    const int n = blockIdx.x, bb = n & 63, qt = n >> 6;
    const int q0 = qt * 64 + wv * 16;
    const int* maskb = mask + bb * 512;

    auto stageK = [&](int dst, int kt) {   // XOR-swizzled via source chunk
        #pragma unroll
        for (int it = 0; it < 4; ++it) {
            int r2 = wv * 8 + it * 2;
            int r = r2 + (l >> 5), c = l & 31;
            const f16* s = KP + (((size_t)(bb * 512 + kt * 32 + r)) << 8) + ((c ^ (r & 7)) << 3);
            stage16(s, &Ks[dst][r2 << 8], l);
        }
    };
    auto stageV = [&](int dst, int kt) {   // linear: reads are bank-even as-is
        #pragma unroll
        for (int it = 0; it < 4; ++it) {
            int db = wv * 64 + it * 16;
            int d = db + (l >> 2), c = l & 3;
            const f16* s = VT + (((size_t)(bb * 256 + d)) << 9) + kt * 32 + (c << 3);
            stage16(s, &Vs[dst][db << 5], l);
        }
    };

    // Q fragments (scale already folded into QP/KP at projection)
    f16x8 qf[8];
    const f16* qrow = QP + (((size_t)(bb * 512 + q0 + lr)) << 8);
    #pragma unroll
    for (int kk = 0; kk < 8; ++kk) qf[kk] = *(const f16x8*)(qrow + kk * 32 + lg * 8);

    f32x4 O[16] = {};
    float m[4], ls[4];
    #pragma unroll
    for (int r = 0; r < 4; ++r) { m[r] = -INFINITY; ls[r] = 0.f; }

    int mk0c = maskb[lr], mk1c = maskb[16 + lr], mk0n = 0, mk1n = 0;
    stageK(0, 0); stageV(0, 0);
    __syncthreads();

    for (int kt = 0; kt < 16; ++kt) {
        const int cur = kt & 1;
        if (kt < 15) {
            stageK(cur ^ 1, kt + 1);
            stageV(cur ^ 1, kt + 1);
            mk0n = maskb[(kt + 1) * 32 + lr];
            mk1n = maskb[(kt + 1) * 32 + 16 + lr];
        }
        // S = Q K^T (32 kpos)
        f32x4 s0 = {}, s1 = {};
        #pragma unroll
        for (int kk = 0; kk < 8; ++kk) {
            int dk = kk * 32 + lg * 8;
            f16x8 b0 = *(const f16x8*)&Ks[cur][(lr << 8) + (dk ^ ((lr & 7) << 3))];
            f16x8 b1 = *(const f16x8*)&Ks[cur][((16 + lr) << 8) + (dk ^ ((lr & 7) << 3))];
            s0 = MFMA16(qf[kk], b0, s0);
            s1 = MFMA16(qf[kk], b1, s1);
        }
        // online softmax; lane owns rows lg*4+rg, cols lr / 16+lr
        float fsc[4];
        #pragma unroll
        for (int rg = 0; rg < 4; ++rg) {
            float v0 = mk0c ? s0[rg] : NEG_INF;
            float v1 = mk1c ? s1[rg] : NEG_INF;
            float tm = fmaxf(v0, v1);
            tm = fmaxf(tm, __shfl_xor(tm, 1));
            tm = fmaxf(tm, __shfl_xor(tm, 2));
            tm = fmaxf(tm, __shfl_xor(tm, 4));
            tm = fmaxf(tm, __shfl_xor(tm, 8));
            float mn = fmaxf(m[rg], tm);
            float f = __expf(m[rg] - mn);
            float p0 = __expf(v0 - mn);
            float p1 = __expf(v1 - mn);
            float rs = p0 + p1;
            rs += __shfl_xor(rs, 1);
            rs += __shfl_xor(rs, 2);
            rs += __shfl_xor(rs, 4);
            rs += __shfl_xor(rs, 8);
            ls[rg] = ls[rg] * f + rs;
            m[rg] = mn; fsc[rg] = f;
            int qq = lg * 4 + rg;
            Pw[wv][(qq << 5) + (lr ^ ((qq & 3) << 3))] = (f16)p0;
            Pw[wv][(qq << 5) + ((16 + lr) ^ ((qq & 3) << 3))] = (f16)p1;
        }
        #pragma unroll
        for (int nt = 0; nt < 16; ++nt) {
            #pragma unroll
            for (int rg = 0; rg < 4; ++rg) O[nt][rg] *= fsc[rg];
        }
        // PV (same-wave LDS RAW on Pw is in-order)
        f16x8 pa = *(const f16x8*)&Pw[wv][(lr << 5) + ((lg * 8) ^ ((lr & 3) << 3))];
        #pragma unroll
        for (int nt = 0; nt < 16; ++nt) {
            f16x8 vb = *(const f16x8*)&Vs[cur][((nt * 16 + lr) << 5) + lg * 8];
            O[nt] = MFMA16(pa, vb, O[nt]);
        }
        if (kt < 15) { __syncthreads(); mk0c = mk0n; mk1c = mk1n; }
    }

    // epilogue: normalize, sum this wave's 16 rows, atomic mean accumulate
    float rls[4];
    #pragma unroll
    for (int rg = 0; rg < 4; ++rg) rls[rg] = 1.0f / ls[rg];
    #pragma unroll
    for (int nt = 0; nt < 16; ++nt) {
        float v = 0.f;
        #pragma unroll
        for (int rg = 0; rg < 4; ++rg) v += O[nt][rg] * rls[rg];
        v += __shfl_xor(v, 16);
        v += __shfl_xor(v, 32);
        if (l < 16) atomicAdd(&out[bb * 256 + nt * 16 + l], v * (1.f / 512.f));
    }
}

// ---------------------------------------------------------------------------
extern "C" void kernel_launch(void* const* d_in, const int* in_sizes, int n_in,
                              void* d_out, int out_size, void* d_ws, size_t ws_size,
                              hipStream_t stream) {
    const float* q  = (const float*)d_in[0];
    const float* k  = (const float*)d_in[1];
    const float* v  = (const float*)d_in[2];
    const float* W  = (const float*)d_in[3];
    const int* mask = (const int*)d_in[4];

    // ws: QP f16 16MB | KP f16 16MB | VT f16 16MB | PE f32 512KB | WT f16 128KB
    f16*   QP = (f16*)d_ws;
    f16*   KP = QP + (size_t)32768 * 256;
    f16*   VT = KP + (size_t)32768 * 256;
    float* PE = (float*)((char*)d_ws + (size_t)48 * 1024 * 1024);
    f16*   WT = (f16*)((char*)d_ws + (size_t)48 * 1024 * 1024 + 512 * 1024);

    pe_kernel<<<512, 256, 0, stream>>>(PE);
    wt_kernel<<<256, 256, 0, stream>>>(W, WT);
    vt_kernel<<<dim3(8, 64), 256, 0, stream>>>(v, VT);
    proj_kernel<<<1024, 256, 0, stream>>>(q, k, WT, PE, QP);
    hipMemsetAsync(d_out, 0, 64 * 256 * sizeof(float), stream);
    attn_kernel<<<512, 256, 0, stream>>>(QP, KP, VT, mask, (float*)d_out);
}

// Round 5
// 179.844 us; speedup vs baseline: 1.6387x; 1.1217x over previous
//
#include <hip/hip_runtime.h>

// B=64, S=512, D=256
#define NEG_INF (-4294967295.0f)

typedef _Float16 f16;
typedef _Float16 f16x8 __attribute__((ext_vector_type(8)));
typedef _Float16 f16x4v __attribute__((ext_vector_type(4)));
typedef float f32x4 __attribute__((ext_vector_type(4)));

#define MFMA16(a,b,c) __builtin_amdgcn_mfma_f32_16x16x32_f16((a),(b),(c),0,0,0)

#if defined(__has_builtin)
#if __has_builtin(__builtin_amdgcn_global_load_lds)
#define HAS_GLD 1
#endif
#endif

// async 16B global->LDS; dest = lds_base + lane*16 (wave-uniform base)
__device__ __forceinline__ void stage16(const void* g, void* lds_base, int lane) {
#ifdef HAS_GLD
    __builtin_amdgcn_global_load_lds(
        (const __attribute__((address_space(1))) unsigned int*)g,
        (__attribute__((address_space(3))) unsigned int*)lds_base, 16, 0, 0);
#else
    ((f16x8*)lds_base)[lane] = *(const f16x8*)g;
#endif
}

// ---------------------------------------------------------------------------
// PE table f32 [512][256]
// ---------------------------------------------------------------------------
__global__ __launch_bounds__(256) void pe_kernel(float* __restrict__ pe) {
    int idx = blockIdx.x * 256 + threadIdx.x;
    int s = idx >> 8, d = idx & 255;
    float x = (float)(d & ~1) * (1.f / 256.f);
    float rate = exp2f(x * -13.287712379549449f);   // 10000^-x
    float ang = (float)s * rate;
    pe[idx] = (d & 1) ? cosf(ang) : sinf(ang);
}

// W^T f16 [e][d] = W[d][e]
__global__ __launch_bounds__(256) void wt_kernel(const float* __restrict__ W,
                                                 f16* __restrict__ WT) {
    int e = blockIdx.x, d = threadIdx.x;
    WT[(e << 8) + d] = (f16)W[(d << 8) + e];
}

// ---------------------------------------------------------------------------
// Projection: rows 0..32767=q, 32768..65535=k. out = relu((x+pe)@W)*0.25, f16.
// (identical to the round-2-verified kernel)
// ---------------------------------------------------------------------------
__global__ __launch_bounds__(256) void proj_kernel(const float* __restrict__ q,
                                                   const float* __restrict__ k,
                                                   const f16* __restrict__ WT,
                                                   const float* __restrict__ pe,
                                                   f16* __restrict__ outp) {
    __shared__ __align__(16) f16 As[2][64 * 64];
    __shared__ __align__(16) f16 WTs[2][256 * 64];
    const int t = threadIdx.x, l = t & 63, wv = t >> 6, lr = l & 15, lg = l >> 4;
    const int r0 = blockIdx.x * 64;
    const float* src = (r0 < 32768) ? q : k;
    const int rb = r0 & 32767;

    float4 av[4], pv[4];
    auto loadA = [&](int kc) {
        #pragma unroll
        for (int it = 0; it < 4; ++it) {
            int r = it * 16 + (t >> 4), d = (t & 15) * 4;
            av[it] = *(const float4*)(src + (size_t)(rb + r) * 256 + kc * 64 + d);
            pv[it] = *(const float4*)(pe + ((rb + r) & 511) * 256 + kc * 64 + d);
        }
    };
    auto writeA = [&](int dst) {
        #pragma unroll
        for (int it = 0; it < 4; ++it) {
            int r = it * 16 + (t >> 4), d = (t & 15) * 4;
            f16x4v h;
            h[0] = (f16)(av[it].x + pv[it].x); h[1] = (f16)(av[it].y + pv[it].y);
            h[2] = (f16)(av[it].z + pv[it].z); h[3] = (f16)(av[it].w + pv[it].w);
            *(f16x4v*)&As[dst][(r << 6) + (d ^ ((r & 7) << 3))] = h;
        }
    };
    auto stageW = [&](int dst, int kc) {   // swizzle via per-lane source chunk
        #pragma unroll
        for (int it = 0; it < 8; ++it) {
            int eb = wv * 64 + it * 8;
            int e = eb + (l >> 3), c = l & 7;
            const f16* s = WT + (e << 8) + kc * 64 + ((c ^ (e & 7)) << 3);
            stage16(s, &WTs[dst][eb << 6], l);
        }
    };

    f32x4 acc[16] = {};
    loadA(0); stageW(0, 0); writeA(0);
    __syncthreads();

    for (int kc = 0; kc < 4; ++kc) {
        int cur = kc & 1;
        if (kc < 3) { loadA(kc + 1); stageW(cur ^ 1, kc + 1); }
        #pragma unroll
        for (int kk = 0; kk < 2; ++kk) {
            int dk = kk * 32 + lg * 8;
            f16x8 a = *(const f16x8*)&As[cur][((wv * 16 + lr) << 6) + (dk ^ ((lr & 7) << 3))];
            #pragma unroll
            for (int nt = 0; nt < 16; ++nt) {
                int e = nt * 16 + lr;
                f16x8 b = *(const f16x8*)&WTs[cur][(e << 6) + (dk ^ ((lr & 7) << 3))];
                acc[nt] = MFMA16(a, b, acc[nt]);
            }
        }
        if (kc < 3) { writeA(cur ^ 1); __syncthreads(); }
    }

    // epilogue: relu * 0.25 (folds 1/sqrt(D)), LDS bounce -> coalesced 16B stores.
    f16* Rb = &WTs[0][0] + wv * 4096;
    #pragma unroll
    for (int nt = 0; nt < 16; ++nt) {
        #pragma unroll
        for (int rg = 0; rg < 4; ++rg) {
            int rr = lg * 4 + rg, col = nt * 16 + lr;
            float v = acc[nt][rg];
            v = v > 0.f ? v * 0.25f : 0.f;
            Rb[rr * 256 + ((((col >> 3) ^ (rr & 7)) << 3) | (col & 7))] = (f16)v;
        }
    }
    #pragma unroll
    for (int it = 0; it < 8; ++it) {
        int row = it * 2 + (l >> 5), c = l & 31;
        f16x8 v8 = *(const f16x8*)&Rb[row * 256 + ((c ^ (row & 7)) << 3)];
        *(f16x8*)(outp + (((size_t)(r0 + wv * 16 + row)) << 8) + c * 8) = v8;
    }
}

// ---------------------------------------------------------------------------
// Attention column-weights: w[b,k] = sum_q exp(S[q,k]) / l[q], l[q]=sum_k exp.
// |S| <= |q||k| ~ 6 post-relu-scaled, so NO max-shift is needed: exp in f32,
// store p as f16 (plain casts), accumulate l from the QUANTIZED p values.
// All-masked batch: p=exp(NEG_INF)=0 -> l=0 -> uniform 1/512 fallback.
// Grid 512: bb=n&63 (XCD locality), qt=n>>6.
// ---------------------------------------------------------------------------
__global__ __launch_bounds__(256) void attn_kernel(const f16* __restrict__ QP,
                                                   const f16* __restrict__ KP,
                                                   const int* __restrict__ mask,
                                                   float* __restrict__ wglob) {
    __shared__ __align__(16) f16 Ks[2][32 * 256];
    __shared__ float ws[4][512];
    const int t = threadIdx.x, l = t & 63, wv = t >> 6, lr = l & 15, lg = l >> 4;
    const int n = blockIdx.x, bb = n & 63, qt = n >> 6;
    const int q0 = qt * 64 + wv * 16;
    const int* maskb = mask + bb * 512;

    auto stageK = [&](int dst, int kt) {   // XOR-swizzled via pre-swizzled source
        #pragma unroll
        for (int it = 0; it < 4; ++it) {
            int r2 = wv * 8 + it * 2;
            int r = r2 + (l >> 5), c = l & 31;
            const f16* s = KP + (((size_t)(bb * 512 + kt * 32 + r)) << 8) + ((c ^ (r & 7)) << 3);
            stage16(s, &Ks[dst][r2 << 8], l);
        }
    };

    // Q fragments (1/sqrt(D) folded at projection: 0.25 into each of Q,K)
    f16x8 qf[8];
    const f16* qrow = QP + (((size_t)(bb * 512 + q0 + lr)) << 8);
    #pragma unroll
    for (int kk = 0; kk < 8; ++kk) qf[kk] = *(const f16x8*)(qrow + kk * 32 + lg * 8);

    // mask bits for this lane's two k-columns across 16 tiles
    unsigned mb0 = 0, mb1 = 0;
    #pragma unroll
    for (int kt = 0; kt < 16; ++kt) {
        mb0 |= (maskb[kt * 32 + lr] ? 1u : 0u) << kt;
        mb1 |= (maskb[kt * 32 + 16 + lr] ? 1u : 0u) << kt;
    }

    float lacc[4] = {0.f, 0.f, 0.f, 0.f};
    f16 Pst[16][8];

    stageK(0, 0);
    __syncthreads();

    #pragma unroll
    for (int kt = 0; kt < 16; ++kt) {
        const int cur = kt & 1;
        if (kt < 15) stageK(cur ^ 1, kt + 1);
        f32x4 s0 = {}, s1 = {};
        #pragma unroll
        for (int kk = 0; kk < 8; ++kk) {
            int dk = kk * 32 + lg * 8;
            f16x8 b0 = *(const f16x8*)&Ks[cur][(lr << 8) + (dk ^ ((lr & 7) << 3))];
            f16x8 b1 = *(const f16x8*)&Ks[cur][((16 + lr) << 8) + (dk ^ ((lr & 7) << 3))];
            s0 = MFMA16(qf[kk], b0, s0);
            s1 = MFMA16(qf[kk], b1, s1);
        }
        #pragma unroll
        for (int rg = 0; rg < 4; ++rg) {
            float p0 = __expf(((mb0 >> kt) & 1) ? s0[rg] : NEG_INF);  // masked -> 0
            float p1 = __expf(((mb1 >> kt) & 1) ? s1[rg] : NEG_INF);
            f16 h0 = (f16)p0, h1 = (f16)p1;
            Pst[kt][rg] = h0;
            Pst[kt][4 + rg] = h1;
            lacc[rg] += (float)h0 + (float)h1;    // l from quantized p
        }
        if (kt < 15) __syncthreads();
    }

    // complete l per row (sum over 16 lr lanes; lg-group owns rows lg*4+rg)
    #pragma unroll
    for (int rg = 0; rg < 4; ++rg) {
        float s = lacc[rg];
        s += __shfl_xor(s, 1); s += __shfl_xor(s, 2);
        s += __shfl_xor(s, 4); s += __shfl_xor(s, 8);
        lacc[rg] = s;
    }
    float rl[4];
    float bsum = 0.f;   // uniform fallback for all-masked batch (l==0)
    #pragma unroll
    for (int rg = 0; rg < 4; ++rg) {
        if (lacc[rg] > 0.f) { rl[rg] = 1.0f / lacc[rg]; }
        else                { rl[rg] = 0.f; bsum += 1.f / 512.f; }
    }

    // w partials: weight by 1/l, reduce across lg groups, store per-wave slice
    #pragma unroll
    for (int kt = 0; kt < 16; ++kt) {
        float w0 = (float)Pst[kt][0] * rl[0] + (float)Pst[kt][1] * rl[1]
                 + (float)Pst[kt][2] * rl[2] + (float)Pst[kt][3] * rl[3] + bsum;
        float w1 = (float)Pst[kt][4] * rl[0] + (float)Pst[kt][5] * rl[1]
                 + (float)Pst[kt][6] * rl[2] + (float)Pst[kt][7] * rl[3] + bsum;
        w0 += __shfl_xor(w0, 16); w0 += __shfl_xor(w0, 32);
        w1 += __shfl_xor(w1, 16); w1 += __shfl_xor(w1, 32);
        if (lg == 0) {
            ws[wv][kt * 32 + lr] = w0;
            ws[wv][kt * 32 + 16 + lr] = w1;
        }
    }
    __syncthreads();
    #pragma unroll
    for (int i = 0; i < 2; ++i) {
        int kk = t + i * 256;
        float s = ws[0][kk] + ws[1][kk] + ws[2][kk] + ws[3][kk];
        atomicAdd(&wglob[bb * 512 + kk], s);
    }
}

// ---------------------------------------------------------------------------
// out[b,d] = (1/512) * sum_k w[b,k] V[b,k,d].  Grid 512: bb=n&63, 8 k-chunks.
// ---------------------------------------------------------------------------
__global__ __launch_bounds__(256) void wv_kernel(const float* __restrict__ wglob,
                                                 const float* __restrict__ V,
                                                 float* __restrict__ out) {
    const int n = blockIdx.x, bb = n & 63, ks = n >> 6;
    const int d = threadIdx.x;
    const float* wr = wglob + bb * 512 + ks * 64;
    const float* vb = V + ((((size_t)bb) * 512 + ks * 64) << 8) + d;
    float acc = 0.f;
    #pragma unroll 8
    for (int kk = 0; kk < 64; ++kk) acc = fmaf(wr[kk], vb[(size_t)kk << 8], acc);
    atomicAdd(&out[bb * 256 + d], acc * (1.f / 512.f));
}

// ---------------------------------------------------------------------------
extern "C" void kernel_launch(void* const* d_in, const int* in_sizes, int n_in,
                              void* d_out, int out_size, void* d_ws, size_t ws_size,
                              hipStream_t stream) {
    const float* q  = (const float*)d_in[0];
    const float* k  = (const float*)d_in[1];
    const float* v  = (const float*)d_in[2];
    const float* W  = (const float*)d_in[3];
    const int* mask = (const int*)d_in[4];

    char* ws = (char*)d_ws;
    f16*   QP = (f16*)ws;                               // 16 MB
    f16*   KP = (f16*)(ws + 16777216);                  // 16 MB
    float* PE = (float*)(ws + 33554432);                // 512 KB
    f16*   WT = (f16*)(ws + 34078720);                  // 128 KB
    float* WG = (float*)(ws + 34209792);                // 128 KB

    pe_kernel<<<512, 256, 0, stream>>>(PE);
    wt_kernel<<<256, 256, 0, stream>>>(W, WT);
    proj_kernel<<<1024, 256, 0, stream>>>(q, k, WT, PE, QP);
    (void)hipMemsetAsync(WG, 0, 64 * 512 * sizeof(float), stream);
    (void)hipMemsetAsync(d_out, 0, 64 * 256 * sizeof(float), stream);
    attn_kernel<<<512, 256, 0, stream>>>(QP, KP, mask, WG);
    wv_kernel<<<512, 256, 0, stream>>>(WG, v, (float*)d_out);
}

// Round 6
// 175.945 us; speedup vs baseline: 1.6750x; 1.0222x over previous
//
#include <hip/hip_runtime.h>

// B=64, S=512, D=256
#define NEG_INF (-4294967295.0f)

typedef _Float16 f16;
typedef _Float16 f16x8 __attribute__((ext_vector_type(8)));
typedef _Float16 f16x4v __attribute__((ext_vector_type(4)));
typedef float f32x4 __attribute__((ext_vector_type(4)));

#define MFMA16(a,b,c) __builtin_amdgcn_mfma_f32_16x16x32_f16((a),(b),(c),0,0,0)

#if defined(__has_builtin)
#if __has_builtin(__builtin_amdgcn_global_load_lds)
#define HAS_GLD 1
#endif
#endif

// async 16B global->LDS; dest = lds_base + lane*16 (wave-uniform base)
__device__ __forceinline__ void stage16(const void* g, void* lds_base, int lane) {
#ifdef HAS_GLD
    __builtin_amdgcn_global_load_lds(
        (const __attribute__((address_space(1))) unsigned int*)g,
        (__attribute__((address_space(3))) unsigned int*)lds_base, 16, 0, 0);
#else
    ((f16x8*)lds_base)[lane] = *(const f16x8*)g;
#endif
}

// ---------------------------------------------------------------------------
// Fused setup: PE table (blocks 0..511), W^T f16 (512..767), zero WG (768),
// zero out (769). One node instead of four.
// ---------------------------------------------------------------------------
__global__ __launch_bounds__(256) void setup_kernel(const float* __restrict__ W,
                                                    float* __restrict__ pe,
                                                    f16* __restrict__ WT,
                                                    float* __restrict__ WG,
                                                    float* __restrict__ out) {
    const int bid = blockIdx.x, t = threadIdx.x;
    if (bid < 512) {                       // PE: sinusoidal table f32 [512][256]
        int idx = bid * 256 + t;
        int s = idx >> 8, d = idx & 255;
        float x = (float)(d & ~1) * (1.f / 256.f);
        float rate = exp2f(x * -13.287712379549449f);   // 10000^-x
        float ang = (float)s * rate;
        pe[idx] = (d & 1) ? cosf(ang) : sinf(ang);
    } else if (bid < 768) {                // W^T[e][d] = W[d][e]
        int e = bid - 512, d = t;
        WT[(e << 8) + d] = (f16)W[(d << 8) + e];
    } else if (bid == 768) {               // zero w-accumulator (64*512 f32)
        #pragma unroll
        for (int i = 0; i < 128; ++i) WG[i * 256 + t] = 0.f;
    } else {                               // zero output (64*256 f32)
        #pragma unroll
        for (int i = 0; i < 64; ++i) out[i * 256 + t] = 0.f;
    }
}

// ---------------------------------------------------------------------------
// Projection: rows 0..32767=q, 32768..65535=k. out = relu((x+pe)@W)*0.25, f16.
// 1024 threads (16 waves), 256 rows x 256 cols per block, grid=256 (1/CU).
// LDS 128KB: A dbuf 2x32KB + W^T dbuf 2x32KB; K double-buffered by 64.
// ---------------------------------------------------------------------------
__global__ __launch_bounds__(1024, 4) void proj_kernel(const float* __restrict__ q,
                                                       const float* __restrict__ k,
                                                       const f16* __restrict__ WT,
                                                       const float* __restrict__ pe,
                                                       f16* __restrict__ outp) {
    __shared__ __align__(16) f16 lds[65536];            // 128 KB
    f16* const As0 = lds;                               // [256][64] swizzled
    f16* const As1 = lds + 16384;
    f16* const Ws0 = lds + 32768;                       // [256 e][64 d] swizzled
    f16* const Ws1 = lds + 49152;

    const int t = threadIdx.x, l = t & 63, wv = t >> 6, lr = l & 15, lg = l >> 4;
    const int r0 = blockIdx.x * 256;
    const float* src = (r0 < 32768) ? q : k;
    const int rb = r0 & 32767;

    float4 av[4], pv[4];
    auto loadA = [&](int kc) {
        #pragma unroll
        for (int it = 0; it < 4; ++it) {
            int r = it * 64 + (t >> 4), d = (t & 15) * 4;
            av[it] = *(const float4*)(src + (size_t)(rb + r) * 256 + kc * 64 + d);
            pv[it] = *(const float4*)(pe + ((rb + r) & 511) * 256 + kc * 64 + d);
        }
    };
    auto writeA = [&](f16* dst) {
        #pragma unroll
        for (int it = 0; it < 4; ++it) {
            int r = it * 64 + (t >> 4), d = (t & 15) * 4;
            f16x4v h;
            h[0] = (f16)(av[it].x + pv[it].x); h[1] = (f16)(av[it].y + pv[it].y);
            h[2] = (f16)(av[it].z + pv[it].z); h[3] = (f16)(av[it].w + pv[it].w);
            *(f16x4v*)&dst[(r << 6) + (d ^ ((r & 7) << 3))] = h;
        }
    };
    auto stageW = [&](f16* dst, int kc) {   // swizzle via per-lane source chunk
        #pragma unroll
        for (int it = 0; it < 2; ++it) {
            int eb = wv * 16 + it * 8;
            int e = eb + (l >> 3), c = l & 7;
            const f16* s = WT + (e << 8) + kc * 64 + ((c ^ (e & 7)) << 3);
            stage16(s, &dst[eb << 6], l);
        }
    };

    f32x4 acc[16] = {};
    loadA(0); stageW(Ws0, 0); writeA(As0);
    __syncthreads();

    #pragma unroll
    for (int kc = 0; kc < 4; ++kc) {
        f16* const Ac = (kc & 1) ? As1 : As0;
        f16* const Wc = (kc & 1) ? Ws1 : Ws0;
        f16* const An = (kc & 1) ? As0 : As1;
        f16* const Wn = (kc & 1) ? Ws0 : Ws1;
        if (kc < 3) { loadA(kc + 1); stageW(Wn, kc + 1); }
        #pragma unroll
        for (int kk = 0; kk < 2; ++kk) {
            int dk = kk * 32 + lg * 8;
            f16x8 a = *(const f16x8*)&Ac[((wv * 16 + lr) << 6) + (dk ^ ((lr & 7) << 3))];
            #pragma unroll
            for (int nt = 0; nt < 16; ++nt) {
                int e = nt * 16 + lr;
                f16x8 b = *(const f16x8*)&Wc[(e << 6) + (dk ^ ((lr & 7) << 3))];
                acc[nt] = MFMA16(a, b, acc[nt]);
            }
        }
        if (kc < 3) { writeA(An); __syncthreads(); }
    }

    // epilogue: relu * 0.25 (folds 1/sqrt(D)); all LDS dead after this barrier
    // -> per-wave 8KB bounce slice, then coalesced 16B stores.
    __syncthreads();
    f16* Rb = lds + wv * 4096;
    #pragma unroll
    for (int nt = 0; nt < 16; ++nt) {
        #pragma unroll
        for (int rg = 0; rg < 4; ++rg) {
            int rr = lg * 4 + rg, col = nt * 16 + lr;
            float v = acc[nt][rg];
            v = v > 0.f ? v * 0.25f : 0.f;
            Rb[rr * 256 + ((((col >> 3) ^ (rr & 7)) << 3) | (col & 7))] = (f16)v;
        }
    }
    #pragma unroll
    for (int it = 0; it < 8; ++it) {
        int row = it * 2 + (l >> 5), c = l & 31;
        f16x8 v8 = *(const f16x8*)&Rb[row * 256 + ((c ^ (row & 7)) << 3)];
        *(f16x8*)(outp + (((size_t)(r0 + wv * 16 + row)) << 8) + c * 8) = v8;
    }
}

// ---------------------------------------------------------------------------
// Attention column-weights: w[b,k] = sum_q exp(S[q,k]) / l[q], l[q]=sum_k exp.
// |S| <= |q||k| ~ 6 post-relu-scaled, so NO max-shift is needed: exp in f32,
// store p as f16 (plain casts), accumulate l from the QUANTIZED p values.
// All-masked batch: p=exp(NEG_INF)=0 -> l=0 -> uniform 1/512 fallback.
// Grid 512: bb=n&63 (XCD locality), qt=n>>6.  (round-5-verified)
// ---------------------------------------------------------------------------
__global__ __launch_bounds__(256) void attn_kernel(const f16* __restrict__ QP,
                                                   const f16* __restrict__ KP,
                                                   const int* __restrict__ mask,
                                                   float* __restrict__ wglob) {
    __shared__ __align__(16) f16 Ks[2][32 * 256];
    __shared__ float ws[4][512];
    const int t = threadIdx.x, l = t & 63, wv = t >> 6, lr = l & 15, lg = l >> 4;
    const int n = blockIdx.x, bb = n & 63, qt = n >> 6;
    const int q0 = qt * 64 + wv * 16;
    const int* maskb = mask + bb * 512;

    auto stageK = [&](int dst, int kt) {   // XOR-swizzled via pre-swizzled source
        #pragma unroll
        for (int it = 0; it < 4; ++it) {
            int r2 = wv * 8 + it * 2;
            int r = r2 + (l >> 5), c = l & 31;
            const f16* s = KP + (((size_t)(bb * 512 + kt * 32 + r)) << 8) + ((c ^ (r & 7)) << 3);
            stage16(s, &Ks[dst][r2 << 8], l);
        }
    };

    // Q fragments (1/sqrt(D) folded at projection: 0.25 into each of Q,K)
    f16x8 qf[8];
    const f16* qrow = QP + (((size_t)(bb * 512 + q0 + lr)) << 8);
    #pragma unroll
    for (int kk = 0; kk < 8; ++kk) qf[kk] = *(const f16x8*)(qrow + kk * 32 + lg * 8);

    // mask bits for this lane's two k-columns across 16 tiles
    unsigned mb0 = 0, mb1 = 0;
    #pragma unroll
    for (int kt = 0; kt < 16; ++kt) {
        mb0 |= (maskb[kt * 32 + lr] ? 1u : 0u) << kt;
        mb1 |= (maskb[kt * 32 + 16 + lr] ? 1u : 0u) << kt;
    }

    float lacc[4] = {0.f, 0.f, 0.f, 0.f};
    f16 Pst[16][8];

    stageK(0, 0);
    __syncthreads();

    #pragma unroll
    for (int kt = 0; kt < 16; ++kt) {
        const int cur = kt & 1;
        if (kt < 15) stageK(cur ^ 1, kt + 1);
        f32x4 s0 = {}, s1 = {};
        #pragma unroll
        for (int kk = 0; kk < 8; ++kk) {
            int dk = kk * 32 + lg * 8;
            f16x8 b0 = *(const f16x8*)&Ks[cur][(lr << 8) + (dk ^ ((lr & 7) << 3))];
            f16x8 b1 = *(const f16x8*)&Ks[cur][((16 + lr) << 8) + (dk ^ ((lr & 7) << 3))];
            s0 = MFMA16(qf[kk], b0, s0);
            s1 = MFMA16(qf[kk], b1, s1);
        }
        #pragma unroll
        for (int rg = 0; rg < 4; ++rg) {
            float p0 = __expf(((mb0 >> kt) & 1) ? s0[rg] : NEG_INF);  // masked -> 0
            float p1 = __expf(((mb1 >> kt) & 1) ? s1[rg] : NEG_INF);
            f16 h0 = (f16)p0, h1 = (f16)p1;
            Pst[kt][rg] = h0;
            Pst[kt][4 + rg] = h1;
            lacc[rg] += (float)h0 + (float)h1;    // l from quantized p
        }
        if (kt < 15) __syncthreads();
    }

    // complete l per row (sum over 16 lr lanes; lg-group owns rows lg*4+rg)
    #pragma unroll
    for (int rg = 0; rg < 4; ++rg) {
        float s = lacc[rg];
        s += __shfl_xor(s, 1); s += __shfl_xor(s, 2);
        s += __shfl_xor(s, 4); s += __shfl_xor(s, 8);
        lacc[rg] = s;
    }
    float rl[4];
    float bsum = 0.f;   // uniform fallback for all-masked batch (l==0)
    #pragma unroll
    for (int rg = 0; rg < 4; ++rg) {
        if (lacc[rg] > 0.f) { rl[rg] = 1.0f / lacc[rg]; }
        else                { rl[rg] = 0.f; bsum += 1.f / 512.f; }
    }

    // w partials: weight by 1/l, reduce across lg groups, store per-wave slice
    #pragma unroll
    for (int kt = 0; kt < 16; ++kt) {
        float w0 = (float)Pst[kt][0] * rl[0] + (float)Pst[kt][1] * rl[1]
                 + (float)Pst[kt][2] * rl[2] + (float)Pst[kt][3] * rl[3] + bsum;
        float w1 = (float)Pst[kt][4] * rl[0] + (float)Pst[kt][5] * rl[1]
                 + (float)Pst[kt][6] * rl[2] + (float)Pst[kt][7] * rl[3] + bsum;
        w0 += __shfl_xor(w0, 16); w0 += __shfl_xor(w0, 32);
        w1 += __shfl_xor(w1, 16); w1 += __shfl_xor(w1, 32);
        if (lg == 0) {
            ws[wv][kt * 32 + lr] = w0;
            ws[wv][kt * 32 + 16 + lr] = w1;
        }
    }
    __syncthreads();
    #pragma unroll
    for (int i = 0; i < 2; ++i) {
        int kk = t + i * 256;
        float s = ws[0][kk] + ws[1][kk] + ws[2][kk] + ws[3][kk];
        atomicAdd(&wglob[bb * 512 + kk], s);
    }
}

// ---------------------------------------------------------------------------
// out[b,d] = (1/512) * sum_k w[b,k] V[b,k,d].  Grid 512: bb=n&63, 8 k-chunks.
// ---------------------------------------------------------------------------
__global__ __launch_bounds__(256) void wv_kernel(const float* __restrict__ wglob,
                                                 const float* __restrict__ V,
                                                 float* __restrict__ out) {
    const int n = blockIdx.x, bb = n & 63, ks = n >> 6;
    const int d = threadIdx.x;
    const float* wr = wglob + bb * 512 + ks * 64;
    const float* vb = V + ((((size_t)bb) * 512 + ks * 64) << 8) + d;
    float acc = 0.f;
    #pragma unroll 8
    for (int kk = 0; kk < 64; ++kk) acc = fmaf(wr[kk], vb[(size_t)kk << 8], acc);
    atomicAdd(&out[bb * 256 + d], acc * (1.f / 512.f));
}

// ---------------------------------------------------------------------------
extern "C" void kernel_launch(void* const* d_in, const int* in_sizes, int n_in,
                              void* d_out, int out_size, void* d_ws, size_t ws_size,
                              hipStream_t stream) {
    const float* q  = (const float*)d_in[0];
    const float* k  = (const float*)d_in[1];
    const float* v  = (const float*)d_in[2];
    const float* W  = (const float*)d_in[3];
    const int* mask = (const int*)d_in[4];

    char* ws = (char*)d_ws;
    f16*   QP = (f16*)ws;                               // 16 MB
    f16*   KP = (f16*)(ws + 16777216);                  // 16 MB
    float* PE = (float*)(ws + 33554432);                // 512 KB
    f16*   WT = (f16*)(ws + 34078720);                  // 128 KB
    float* WG = (float*)(ws + 34209792);                // 128 KB

    setup_kernel<<<770, 256, 0, stream>>>(W, PE, WT, WG, (float*)d_out);
    proj_kernel<<<256, 1024, 0, stream>>>(q, k, WT, PE, QP);
    attn_kernel<<<512, 256, 0, stream>>>(QP, KP, mask, WG);
    wv_kernel<<<512, 256, 0, stream>>>(WG, v, (float*)d_out);
}

// Round 7
// 170.188 us; speedup vs baseline: 1.7316x; 1.0338x over previous
//
#include <hip/hip_runtime.h>

// B=64, S=512, D=256
#define NEG_INF (-4294967295.0f)

typedef _Float16 f16;
typedef _Float16 f16x8 __attribute__((ext_vector_type(8)));
typedef float f32x4 __attribute__((ext_vector_type(4)));

#define MFMA16(a,b,c) __builtin_amdgcn_mfma_f32_16x16x32_f16((a),(b),(c),0,0,0)

#if defined(__has_builtin)
#if __has_builtin(__builtin_amdgcn_global_load_lds)
#define HAS_GLD 1
#endif
#endif

// async 16B global->LDS; dest = lds_base + lane*16 (wave-uniform base)
__device__ __forceinline__ void stage16(const void* g, void* lds_base, int lane) {
#ifdef HAS_GLD
    __builtin_amdgcn_global_load_lds(
        (const __attribute__((address_space(1))) unsigned int*)g,
        (__attribute__((address_space(3))) unsigned int*)lds_base, 16, 0, 0);
#else
    ((f16x8*)lds_base)[lane] = *(const f16x8*)g;
#endif
}

// ---------------------------------------------------------------------------
// Fused setup: PE table (blocks 0..511), W^T f16 (512..767), zero WG (768),
// zero out (769).
// ---------------------------------------------------------------------------
__global__ __launch_bounds__(256) void setup_kernel(const float* __restrict__ W,
                                                    float* __restrict__ pe,
                                                    f16* __restrict__ WT,
                                                    float* __restrict__ WG,
                                                    float* __restrict__ out) {
    const int bid = blockIdx.x, t = threadIdx.x;
    if (bid < 512) {                       // PE: sinusoidal table f32 [512][256]
        int idx = bid * 256 + t;
        int s = idx >> 8, d = idx & 255;
        float x = (float)(d & ~1) * (1.f / 256.f);
        float rate = exp2f(x * -13.287712379549449f);   // 10000^-x
        float ang = (float)s * rate;
        pe[idx] = (d & 1) ? cosf(ang) : sinf(ang);
    } else if (bid < 768) {                // W^T[e][d] = W[d][e]
        int e = bid - 512, d = t;
        WT[(e << 8) + d] = (f16)W[(d << 8) + e];
    } else if (bid == 768) {               // zero w-accumulator (64*512 f32)
        #pragma unroll
        for (int i = 0; i < 128; ++i) WG[i * 256 + t] = 0.f;
    } else {                               // zero output (64*256 f32)
        #pragma unroll
        for (int i = 0; i < 64; ++i) out[i * 256 + t] = 0.f;
    }
}

// ---------------------------------------------------------------------------
// Projection: rows 0..32767=q, 32768..65535=k. out = relu((x+pe)@W)*0.25, f16.
// 256 threads (4 waves x 16 rows), 64 rows x 256 cols per block, grid 1024
// (exactly 4 blocks/CU resident). A loaded DIRECT to MFMA fragments (no LDS);
// W single-buffered 32KB/phase. VGPR cap 128 via launch_bounds -> no spill.
// ---------------------------------------------------------------------------
__global__ __launch_bounds__(256, 4) void proj_kernel(const float* __restrict__ q,
                                                      const float* __restrict__ k,
                                                      const f16* __restrict__ WT,
                                                      const float* __restrict__ pe,
                                                      f16* __restrict__ outp) {
    __shared__ __align__(16) f16 Ws[256 * 64];          // 32 KB, [e][d-chunk] swizzled
    const int t = threadIdx.x, l = t & 63, wv = t >> 6, lr = l & 15, lg = l >> 4;
    const int r0 = blockIdx.x * 64;
    const float* src = (r0 < 32768) ? q : k;
    const int rb = r0 & 32767;

    // A fragments direct from global: lane (lr,lg) covers row rb+wv*16+lr,
    // d = kk*32 + lg*8 .. +8. Wave-wide: 16 rows x 128B contiguous per load.
    const float* arow = src + (size_t)(rb + wv * 16 + lr) * 256;
    const float* prow = pe + (size_t)((rb + wv * 16 + lr) & 511) * 256;
    f16x8 af[8];
    #pragma unroll
    for (int kk = 0; kk < 8; ++kk) {
        int d = kk * 32 + lg * 8;
        float4 a0 = *(const float4*)(arow + d);
        float4 a1 = *(const float4*)(arow + d + 4);
        float4 p0 = *(const float4*)(prow + d);
        float4 p1 = *(const float4*)(prow + d + 4);
        f16x8 h;
        h[0] = (f16)(a0.x + p0.x); h[1] = (f16)(a0.y + p0.y);
        h[2] = (f16)(a0.z + p0.z); h[3] = (f16)(a0.w + p0.w);
        h[4] = (f16)(a1.x + p1.x); h[5] = (f16)(a1.y + p1.y);
        h[6] = (f16)(a1.z + p1.z); h[7] = (f16)(a1.w + p1.w);
        af[kk] = h;
    }

    f32x4 acc[16] = {};
    #pragma unroll
    for (int kc = 0; kc < 4; ++kc) {
        // stage W phase tile [256 e][64 d], swizzled via per-lane source chunk
        #pragma unroll
        for (int it = 0; it < 8; ++it) {
            int eb = wv * 64 + it * 8;
            int e = eb + (l >> 3), c = l & 7;
            const f16* s = WT + (e << 8) + kc * 64 + ((c ^ (e & 7)) << 3);
            stage16(s, &Ws[eb << 6], l);
        }
        __syncthreads();
        #pragma unroll
        for (int kk = 0; kk < 2; ++kk) {
            int dk = kk * 32 + lg * 8;
            f16x8 a = af[kc * 2 + kk];
            #pragma unroll
            for (int nt = 0; nt < 16; ++nt) {
                int e = nt * 16 + lr;
                f16x8 b = *(const f16x8*)&Ws[(e << 6) + (dk ^ ((lr & 7) << 3))];
                acc[nt] = MFMA16(a, b, acc[nt]);
            }
        }
        __syncthreads();    // W reads done before next-phase overwrite
    }

    // epilogue: relu * 0.25 (folds 1/sqrt(D)); W LDS dead -> per-wave 8KB
    // bounce slice, then coalesced 16B stores. (r5-verified pattern)
    f16* Rb = Ws + wv * 4096;
    #pragma unroll
    for (int nt = 0; nt < 16; ++nt) {
        #pragma unroll
        for (int rg = 0; rg < 4; ++rg) {
            int rr = lg * 4 + rg, col = nt * 16 + lr;
            float v = acc[nt][rg];
            v = v > 0.f ? v * 0.25f : 0.f;
            Rb[rr * 256 + ((((col >> 3) ^ (rr & 7)) << 3) | (col & 7))] = (f16)v;
        }
    }
    #pragma unroll
    for (int it = 0; it < 8; ++it) {
        int row = it * 2 + (l >> 5), c = l & 31;
        f16x8 v8 = *(const f16x8*)&Rb[row * 256 + ((c ^ (row & 7)) << 3)];
        *(f16x8*)(outp + (((size_t)(r0 + wv * 16 + row)) << 8) + c * 8) = v8;
    }
}

// ---------------------------------------------------------------------------
// Attention column-weights: w[b,k] = sum_q exp(S[q,k]) / l[q], l[q]=sum_k exp.
// |S| <= |q||k| ~ 6 post-relu-scaled, so NO max-shift is needed: exp in f32,
// store p as f16 (plain casts), accumulate l from the QUANTIZED p values.
// All-masked batch: p=exp(NEG_INF)=0 -> l=0 -> uniform 1/512 fallback.
// Grid 512: bb=n&63 (XCD locality), qt=n>>6.  (round-5-verified)
// ---------------------------------------------------------------------------
__global__ __launch_bounds__(256) void attn_kernel(const f16* __restrict__ QP,
                                                   const f16* __restrict__ KP,
                                                   const int* __restrict__ mask,
                                                   float* __restrict__ wglob) {
    __shared__ __align__(16) f16 Ks[2][32 * 256];
    __shared__ float ws[4][512];
    const int t = threadIdx.x, l = t & 63, wv = t >> 6, lr = l & 15, lg = l >> 4;
    const int n = blockIdx.x, bb = n & 63, qt = n >> 6;
    const int q0 = qt * 64 + wv * 16;
    const int* maskb = mask + bb * 512;

    auto stageK = [&](int dst, int kt) {   // XOR-swizzled via pre-swizzled source
        #pragma unroll
        for (int it = 0; it < 4; ++it) {
            int r2 = wv * 8 + it * 2;
            int r = r2 + (l >> 5), c = l & 31;
            const f16* s = KP + (((size_t)(bb * 512 + kt * 32 + r)) << 8) + ((c ^ (r & 7)) << 3);
            stage16(s, &Ks[dst][r2 << 8], l);
        }
    };

    // Q fragments (1/sqrt(D) folded at projection: 0.25 into each of Q,K)
    f16x8 qf[8];
    const f16* qrow = QP + (((size_t)(bb * 512 + q0 + lr)) << 8);
    #pragma unroll
    for (int kk = 0; kk < 8; ++kk) qf[kk] = *(const f16x8*)(qrow + kk * 32 + lg * 8);

    // mask bits for this lane's two k-columns across 16 tiles
    unsigned mb0 = 0, mb1 = 0;
    #pragma unroll
    for (int kt = 0; kt < 16; ++kt) {
        mb0 |= (maskb[kt * 32 + lr] ? 1u : 0u) << kt;
        mb1 |= (maskb[kt * 32 + 16 + lr] ? 1u : 0u) << kt;
    }

    float lacc[4] = {0.f, 0.f, 0.f, 0.f};
    f16 Pst[16][8];

    stageK(0, 0);
    __syncthreads();

    #pragma unroll
    for (int kt = 0; kt < 16; ++kt) {
        const int cur = kt & 1;
        if (kt < 15) stageK(cur ^ 1, kt + 1);
        f32x4 s0 = {}, s1 = {};
        #pragma unroll
        for (int kk = 0; kk < 8; ++kk) {
            int dk = kk * 32 + lg * 8;
            f16x8 b0 = *(const f16x8*)&Ks[cur][(lr << 8) + (dk ^ ((lr & 7) << 3))];
            f16x8 b1 = *(const f16x8*)&Ks[cur][((16 + lr) << 8) + (dk ^ ((lr & 7) << 3))];
            s0 = MFMA16(qf[kk], b0, s0);
            s1 = MFMA16(qf[kk], b1, s1);
        }
        #pragma unroll
        for (int rg = 0; rg < 4; ++rg) {
            float p0 = __expf(((mb0 >> kt) & 1) ? s0[rg] : NEG_INF);  // masked -> 0
            float p1 = __expf(((mb1 >> kt) & 1) ? s1[rg] : NEG_INF);
            f16 h0 = (f16)p0, h1 = (f16)p1;
            Pst[kt][rg] = h0;
            Pst[kt][4 + rg] = h1;
            lacc[rg] += (float)h0 + (float)h1;    // l from quantized p
        }
        if (kt < 15) __syncthreads();
    }

    // complete l per row (sum over 16 lr lanes; lg-group owns rows lg*4+rg)
    #pragma unroll
    for (int rg = 0; rg < 4; ++rg) {
        float s = lacc[rg];
        s += __shfl_xor(s, 1); s += __shfl_xor(s, 2);
        s += __shfl_xor(s, 4); s += __shfl_xor(s, 8);
        lacc[rg] = s;
    }
    float rl[4];
    float bsum = 0.f;   // uniform fallback for all-masked batch (l==0)
    #pragma unroll
    for (int rg = 0; rg < 4; ++rg) {
        if (lacc[rg] > 0.f) { rl[rg] = 1.0f / lacc[rg]; }
        else                { rl[rg] = 0.f; bsum += 1.f / 512.f; }
    }

    // w partials: weight by 1/l, reduce across lg groups, store per-wave slice
    #pragma unroll
    for (int kt = 0; kt < 16; ++kt) {
        float w0 = (float)Pst[kt][0] * rl[0] + (float)Pst[kt][1] * rl[1]
                 + (float)Pst[kt][2] * rl[2] + (float)Pst[kt][3] * rl[3] + bsum;
        float w1 = (float)Pst[kt][4] * rl[0] + (float)Pst[kt][5] * rl[1]
                 + (float)Pst[kt][6] * rl[2] + (float)Pst[kt][7] * rl[3] + bsum;
        w0 += __shfl_xor(w0, 16); w0 += __shfl_xor(w0, 32);
        w1 += __shfl_xor(w1, 16); w1 += __shfl_xor(w1, 32);
        if (lg == 0) {
            ws[wv][kt * 32 + lr] = w0;
            ws[wv][kt * 32 + 16 + lr] = w1;
        }
    }
    __syncthreads();
    #pragma unroll
    for (int i = 0; i < 2; ++i) {
        int kk = t + i * 256;
        float s = ws[0][kk] + ws[1][kk] + ws[2][kk] + ws[3][kk];
        atomicAdd(&wglob[bb * 512 + kk], s);
    }
}

// ---------------------------------------------------------------------------
// out[b,d] = (1/512) * sum_k w[b,k] V[b,k,d].  Grid 512: bb=n&63, 8 k-chunks.
// ---------------------------------------------------------------------------
__global__ __launch_bounds__(256) void wv_kernel(const float* __restrict__ wglob,
                                                 const float* __restrict__ V,
                                                 float* __restrict__ out) {
    const int n = blockIdx.x, bb = n & 63, ks = n >> 6;
    const int d = threadIdx.x;
    const float* wr = wglob + bb * 512 + ks * 64;
    const float* vb = V + ((((size_t)bb) * 512 + ks * 64) << 8) + d;
    float acc = 0.f;
    #pragma unroll 8
    for (int kk = 0; kk < 64; ++kk) acc = fmaf(wr[kk], vb[(size_t)kk << 8], acc);
    atomicAdd(&out[bb * 256 + d], acc * (1.f / 512.f));
}

// ---------------------------------------------------------------------------
extern "C" void kernel_launch(void* const* d_in, const int* in_sizes, int n_in,
                              void* d_out, int out_size, void* d_ws, size_t ws_size,
                              hipStream_t stream) {
    const float* q  = (const float*)d_in[0];
    const float* k  = (const float*)d_in[1];
    const float* v  = (const float*)d_in[2];
    const float* W  = (const float*)d_in[3];
    const int* mask = (const int*)d_in[4];

    char* ws = (char*)d_ws;
    f16*   QP = (f16*)ws;                               // 16 MB
    f16*   KP = (f16*)(ws + 16777216);                  // 16 MB
    float* PE = (float*)(ws + 33554432);                // 512 KB
    f16*   WT = (f16*)(ws + 34078720);                  // 128 KB
    float* WG = (float*)(ws + 34209792);                // 128 KB

    setup_kernel<<<770, 256, 0, stream>>>(W, PE, WT, WG, (float*)d_out);
    proj_kernel<<<1024, 256, 0, stream>>>(q, k, WT, PE, QP);
    attn_kernel<<<512, 256, 0, stream>>>(QP, KP, mask, WG);
    wv_kernel<<<512, 256, 0, stream>>>(WG, v, (float*)d_out);
}